// Round 8
// baseline (268.462 us; speedup 1.0000x reference)
//
#include <hip/hip_runtime.h>

#define ITERS 20
#define EPS 1e-9f
#define MPW 4   // matrices per wave (software-pipelined)

// Persistent-wave Sinkhorn: 512 blocks x 4 waves = 2048 waves = exactly 2
// resident waves per SIMD; each wave streams MPW=4 matrices through a 2-deep
// E-buffer pipeline so the 16 float4 loads of matrix m+1 are in flight during
// the 20-iteration compute of matrix m (and stores drain under the next
// matrix's compute). This de-phase-serializes memory vs compute, which
// profiling showed as: burst-load ~16us (VALU idle) + compute ~60us (HBM
// idle, avg 2.0TB/s) + burst-store ~16us = 96us dispatch.
//
// Per matrix: lane (bi,bj) owns the 8x8 sub-block rows [8bi,8bi+8), cols
// [8bj,8bj+8) = 64 fp32 E regs. Sinkhorn iterate M = E .* (u v^T): only u,v
// update. Plain scalar fp32 math (pk/dot2/fma_mix all proven rate-neutral or
// worse on gfx950: fp32 vector peak is 1 FMA/lane/cy regardless of packing).
// Cross-lane reduces on the VALU pipe: fused DPP adds for strides 1,2,(7),8
// and permlane16/32_swap for 16/32. u,v updates: u = rcp(p + eps).

template <int CTRL>
__device__ __forceinline__ float dpp_add(float x) {
    int yi = __builtin_amdgcn_update_dpp(0, __float_as_int(x), CTRL, 0xf, 0xf, true);
    return x + __int_as_float(yi);
}

#if __has_builtin(__builtin_amdgcn_permlane16_swap)
// identical inputs: r0+r1 == xor16 butterfly all-reduce, pure VALU
__device__ __forceinline__ float xadd16(float x) {
    unsigned u = __float_as_uint(x);
    auto r = __builtin_amdgcn_permlane16_swap(u, u, false, false);
    return __uint_as_float(r[0]) + __uint_as_float(r[1]);
}
#else
__device__ __forceinline__ float xadd16(float x) {
    return x + __int_as_float(__builtin_amdgcn_ds_swizzle(__float_as_int(x), 0x401F));
}
#endif

#if __has_builtin(__builtin_amdgcn_permlane32_swap)
__device__ __forceinline__ float xadd32(float x) {
    unsigned u = __float_as_uint(x);
    auto r = __builtin_amdgcn_permlane32_swap(u, u, false, false);
    return __uint_as_float(r[0]) + __uint_as_float(r[1]);
}
#else
__device__ __forceinline__ float xadd32(float x) {
    return x + __shfl_xor(x, 32, 64);
}
#endif

// Issue the 16 float4 loads for one matrix into a raw (pre-exp) buffer.
__device__ __forceinline__ void load_raw(float (&d)[8][8], const float* __restrict__ x,
                                         int mat, int bi, int bj) {
    const float4* __restrict__ xin = (const float4*)(x + (size_t)mat * 4096);
    #pragma unroll
    for (int r = 0; r < 8; ++r) {
        float4 lo = xin[(8 * bi + r) * 16 + 2 * bj + 0];
        float4 hi = xin[(8 * bi + r) * 16 + 2 * bj + 1];
        d[r][0] = lo.x; d[r][1] = lo.y; d[r][2] = lo.z; d[r][3] = lo.w;
        d[r][4] = hi.x; d[r][5] = hi.y; d[r][6] = hi.z; d[r][7] = hi.w;
    }
}

__device__ __forceinline__ void exp_inplace(float (&d)[8][8]) {
    #pragma unroll
    for (int r = 0; r < 8; ++r)
        #pragma unroll
        for (int c = 0; c < 8; ++c)
            d[r][c] = __expf(d[r][c]);
}

// 20 Sinkhorn iterations on an in-register 8x8 block; outputs scale vectors.
__device__ __forceinline__ void sink_iters(const float (&b)[8][8],
                                           float (&uu)[8], float (&vv)[8]) {
    #pragma unroll
    for (int i = 0; i < 8; ++i) { uu[i] = 1.0f; vv[i] = 1.0f; }

    for (int it = 0; it < ITERS; ++it) {
        // ---- row phase: p_i = sum_j E[i,j] v_j ; u_i = rcp(p_i + eps) ----
        float p[8];
        #pragma unroll
        for (int r = 0; r < 8; ++r) {
            float se = b[r][0] * vv[0];
            float so = b[r][1] * vv[1];
            se = fmaf(b[r][2], vv[2], se);
            so = fmaf(b[r][3], vv[3], so);
            se = fmaf(b[r][4], vv[4], se);
            so = fmaf(b[r][5], vv[5], so);
            se = fmaf(b[r][6], vv[6], se);
            so = fmaf(b[r][7], vv[7], so);
            p[r] = se + so;
        }
        // all-reduce across the 8 bj lanes (lane bits 0-2) — fused DPP adds
        #pragma unroll
        for (int r = 0; r < 8; ++r) p[r] = dpp_add<0xB1>(p[r]);   // quad_perm xor1
        #pragma unroll
        for (int r = 0; r < 8; ++r) p[r] = dpp_add<0x4E>(p[r]);   // quad_perm xor2
        #pragma unroll
        for (int r = 0; r < 8; ++r) p[r] = dpp_add<0x141>(p[r]);  // row_half_mirror = xor7
        #pragma unroll
        for (int r = 0; r < 8; ++r)
            uu[r] = __builtin_amdgcn_rcpf(p[r] + EPS);

        // ---- col phase: q_j = sum_i E[i,j] u_i ; v_j = rcp(q_j + eps) ----
        float q[8];
        #pragma unroll
        for (int c = 0; c < 8; ++c) {
            float se = b[0][c] * uu[0];
            float so = b[1][c] * uu[1];
            se = fmaf(b[2][c], uu[2], se);
            so = fmaf(b[3][c], uu[3], so);
            se = fmaf(b[4][c], uu[4], se);
            so = fmaf(b[5][c], uu[5], so);
            se = fmaf(b[6][c], uu[6], se);
            so = fmaf(b[7][c], uu[7], so);
            q[c] = se + so;
        }
        // all-reduce across the 8 bi lanes (lane bits 3-5) — all VALU
        #pragma unroll
        for (int c = 0; c < 8; ++c) q[c] = dpp_add<0x128>(q[c]);  // row_ror:8 = xor8
        #pragma unroll
        for (int c = 0; c < 8; ++c) q[c] = xadd16(q[c]);          // permlane16_swap
        #pragma unroll
        for (int c = 0; c < 8; ++c) q[c] = xadd32(q[c]);          // permlane32_swap
        #pragma unroll
        for (int c = 0; c < 8; ++c)
            vv[c] = __builtin_amdgcn_rcpf(q[c] + EPS);
    }
}

__device__ __forceinline__ void store_out(const float (&b)[8][8],
                                          const float (&uu)[8], const float (&vv)[8],
                                          float* __restrict__ out, int mat,
                                          int bi, int bj) {
    float4* __restrict__ o = (float4*)(out + (size_t)mat * 4096);
    #pragma unroll
    for (int r = 0; r < 8; ++r) {
        float ur = uu[r];
        float4 lo, hi;
        lo.x = b[r][0] * ur * vv[0]; lo.y = b[r][1] * ur * vv[1];
        lo.z = b[r][2] * ur * vv[2]; lo.w = b[r][3] * ur * vv[3];
        hi.x = b[r][4] * ur * vv[4]; hi.y = b[r][5] * ur * vv[5];
        hi.z = b[r][6] * ur * vv[6]; hi.w = b[r][7] * ur * vv[7];
        o[(8 * bi + r) * 16 + 2 * bj + 0] = lo;
        o[(8 * bi + r) * 16 + 2 * bj + 1] = hi;
    }
}

__global__ __launch_bounds__(256, 2) void sinkhorn_kernel(
        const float* __restrict__ x, float* __restrict__ out, int nmat) {
    const int lane = threadIdx.x & 63;
    const int wave = threadIdx.x >> 6;
    const int wid  = blockIdx.x * 4 + wave;
    const int mat0 = wid * MPW;
    if (mat0 >= nmat) return;
    const int bi = lane >> 3;   // block-row 0..7 (lane bits 3-5)
    const int bj = lane & 7;    // block-col 0..7 (lane bits 0-2)

    float A[8][8], B[8][8];     // double-buffered raw/E storage
    load_raw(A, x, mat0, bi, bj);

    #pragma unroll
    for (int m = 0; m < MPW; ++m) {
        const int mat = mat0 + m;
        if (mat >= nmat) break;
        float (&cur)[8][8] = (m & 1) ? B : A;   // static after unroll
        float (&nxt)[8][8] = (m & 1) ? A : B;
        // issue next matrix's loads before this matrix's compute
        if (m + 1 < MPW && mat + 1 < nmat)
            load_raw(nxt, x, mat + 1, bi, bj);
        exp_inplace(cur);
        float uu[8], vv[8];
        sink_iters(cur, uu, vv);
        store_out(cur, uu, vv, out, mat, bi, bj);
    }
}

extern "C" void kernel_launch(void* const* d_in, const int* in_sizes, int n_in,
                              void* d_out, int out_size, void* d_ws, size_t ws_size,
                              hipStream_t stream) {
    const float* x = (const float*)d_in[0];
    float* out = (float*)d_out;
    const int nmat = in_sizes[0] / 4096;              // 8192 matrices of 64x64
    const int blocks = (nmat + 4 * MPW - 1) / (4 * MPW);  // 512 blocks at nmat=8192
    sinkhorn_kernel<<<blocks, 256, 0, stream>>>(x, out, nmat);
}